// Round 2
// baseline (20766.444 us; speedup 1.0000x reference)
//
#include <hip/hip_runtime.h>
#include <hip/hip_bf16.h>
#include <math.h>

// Problem constants
#define UN 4096      // units
#define DN 1024      // model dim
#define LN_ 4        // layers
#define HN 16        // heads
#define HD 64        // head dim
#define HIDN 512     // head MLP hidden

// ---------------------------------------------------------------------------
// Generic fp32 GEMM:  C[m][n] = act( sum_k A[m][k] * W[n][k] + bias[n] )
// A: M x K row-major (lda). If ids != nullptr: row m reads A[ids[m]][k] for
//    k < lda and ent[m] at k == lda (fused gather + entropy column, K = lda+1).
// W: N x K row-major (ldw). Scalar fallback when ldw % 4 != 0 (GEMM0).
// Tile 128x128, BK=16, 8x8 per thread, 256 threads.
// Grids are exact: M % 128 == 0, N % 128 == 0 for every call.
// ---------------------------------------------------------------------------
__global__ __launch_bounds__(256)
void gemm_nt(const float* __restrict__ A, const float* __restrict__ W,
             const float* __restrict__ bias, float* __restrict__ C,
             int K, int lda, int ldw, int ldc,
             const int* __restrict__ ids, const float* __restrict__ ent,
             int relu)
{
  __shared__ __align__(16) float As[16][132];  // [k][m], pad 132
  __shared__ __align__(16) float Ws[16][132];  // [k][n]

  const int tid = threadIdx.x;
  const int bm = blockIdx.x, bn = blockIdx.y;
  const int ty = tid >> 4, tx = tid & 15;

  float acc[8][8];
#pragma unroll
  for (int i = 0; i < 8; i++)
#pragma unroll
    for (int j = 0; j < 8; j++) acc[i][j] = 0.f;

  // staging: thread covers (row = tid>>1, k-octet = (tid&1)*8)
  const int srow = tid >> 1;
  const int sk   = (tid & 1) * 8;
  const int ga   = bm * 128 + srow;                    // global A row (< 4096)
  const float* abase = ids ? (A + (size_t)ids[ga] * lda)
                           : (A + (size_t)ga * lda);
  const int gw = bn * 128 + srow;                      // global W row (< N)
  const float* wbase = W + (size_t)gw * ldw;
  const bool wvec = ((ldw & 3) == 0);
  const int kA = ids ? lda : K;   // vectorizable limit for A

  for (int kk = 0; kk < K; kk += 16) {
    const int k0 = kk + sk;
    float av[8], wv[8];
    if (k0 + 8 <= kA) {
      float4 p0 = *(const float4*)(abase + k0);
      float4 p1 = *(const float4*)(abase + k0 + 4);
      av[0]=p0.x; av[1]=p0.y; av[2]=p0.z; av[3]=p0.w;
      av[4]=p1.x; av[5]=p1.y; av[6]=p1.z; av[7]=p1.w;
    } else {
#pragma unroll
      for (int i = 0; i < 8; i++) {
        int k = k0 + i; float v = 0.f;
        if (k < kA) v = abase[k];
        else if (ids && k == lda && k < K) v = ent[ga];  // entropy column
        av[i] = v;
      }
    }
    if (wvec && (k0 + 8 <= K)) {
      float4 p0 = *(const float4*)(wbase + k0);
      float4 p1 = *(const float4*)(wbase + k0 + 4);
      wv[0]=p0.x; wv[1]=p0.y; wv[2]=p0.z; wv[3]=p0.w;
      wv[4]=p1.x; wv[5]=p1.y; wv[6]=p1.z; wv[7]=p1.w;
    } else {
#pragma unroll
      for (int i = 0; i < 8; i++) { int k = k0 + i; wv[i] = (k < K) ? wbase[k] : 0.f; }
    }

    __syncthreads();   // previous tile's reads done before overwrite
#pragma unroll
    for (int i = 0; i < 8; i++) As[sk + i][srow] = av[i];
#pragma unroll
    for (int i = 0; i < 8; i++) Ws[sk + i][srow] = wv[i];
    __syncthreads();

#pragma unroll 4
    for (int k = 0; k < 16; k++) {
      float4 a0 = *(const float4*)&As[k][ty * 8];
      float4 a1 = *(const float4*)&As[k][ty * 8 + 4];
      float4 b0 = *(const float4*)&Ws[k][tx * 8];
      float4 b1 = *(const float4*)&Ws[k][tx * 8 + 4];
      float a[8]  = {a0.x,a0.y,a0.z,a0.w,a1.x,a1.y,a1.z,a1.w};
      float bb[8] = {b0.x,b0.y,b0.z,b0.w,b1.x,b1.y,b1.z,b1.w};
#pragma unroll
      for (int i = 0; i < 8; i++)
#pragma unroll
        for (int j = 0; j < 8; j++)
          acc[i][j] += a[i] * bb[j];
    }
  }

  const int col0 = bn * 128 + tx * 8;
#pragma unroll
  for (int i = 0; i < 8; i++) {
    const int row = bm * 128 + ty * 8 + i;
    float* crow = C + (size_t)row * ldc + col0;
#pragma unroll
    for (int j = 0; j < 8; j += 4) {
      float v0 = acc[i][j+0] + bias[col0+j+0];
      float v1 = acc[i][j+1] + bias[col0+j+1];
      float v2 = acc[i][j+2] + bias[col0+j+2];
      float v3 = acc[i][j+3] + bias[col0+j+3];
      if (relu) { v0=fmaxf(v0,0.f); v1=fmaxf(v1,0.f); v2=fmaxf(v2,0.f); v3=fmaxf(v3,0.f); }
      float4 r; r.x=v0; r.y=v1; r.z=v2; r.w=v3;
      *(float4*)(crow + j) = r;
    }
  }
}

// ---------------------------------------------------------------------------
// RoPE: xr = [rope(x[:, :512], rows), rope(x[:, 512:], cols)]
// Within each 512 block: i in [0,256): x1*c - x2*s ; [256,512): x1*s + x2*c
// theta_i = 10000^(-i/256)
// ---------------------------------------------------------------------------
__global__ __launch_bounds__(256)
void rope_kernel(const float* __restrict__ x, float* __restrict__ xr,
                 const int* __restrict__ ids, const int* __restrict__ nyp)
{
  int idx = blockIdx.x * 256 + threadIdx.x;      // < UN*DN
  int u = idx >> 10, j = idx & 1023;
  int blk = j >> 9, o = j & 511;
  int i = o & 255;
  int t = ids[u];
  int ny = *nyp;
  float pos = (blk == 0) ? (float)(t / ny) : (float)(t % ny);
  float theta = expf((float)i * -0.0359778921f);   // -ln(10000)/256
  float ang = pos * theta;
  float c = cosf(ang), sn = sinf(ang);
  const float* xrow = x + (size_t)u * 1024 + blk * 512;
  float x1 = xrow[i];
  float x2 = xrow[256 + i];
  xr[idx] = (o < 256) ? (x1 * c - x2 * sn) : (x1 * sn + x2 * c);
}

// ---------------------------------------------------------------------------
// Attention: full softmax attention over 4096 keys, per head (hd=64).
// One wave per (head, 64 q-rows). Lane owns one q-row entirely in registers.
// K/V staged in LDS 32 keys per tile; online softmax, conditional rescale.
// q/k read from fused QK buffer (ld 2048; k at column offset 1024).
// ---------------------------------------------------------------------------
__global__ __launch_bounds__(64)
void attn_kernel(const float* __restrict__ qk, const float* __restrict__ v,
                 float* __restrict__ o)
{
  __shared__ __align__(16) float Ks[32][64];
  __shared__ __align__(16) float Vs[32][64];

  const int lane = threadIdx.x;
  const int head = blockIdx.y;
  const int row = blockIdx.x * 64 + lane;

  float qr[64];
  const float* qrow = qk + (size_t)row * 2048 + head * 64;
#pragma unroll
  for (int d4 = 0; d4 < 16; d4++) {
    float4 t = *(const float4*)(qrow + d4 * 4);
    qr[d4*4+0] = t.x; qr[d4*4+1] = t.y; qr[d4*4+2] = t.z; qr[d4*4+3] = t.w;
  }

  float m = -1e30f, lsum = 0.f;
  float acc[64];
#pragma unroll
  for (int d = 0; d < 64; d++) acc[d] = 0.f;

  const float* kbase = qk + 1024 + (size_t)head * 64;  // + key*2048
  const float* vbase = v + (size_t)head * 64;          // + key*1024

  for (int kt = 0; kt < 128; kt++) {
    __syncthreads();
#pragma unroll 8
    for (int i = 0; i < 32; i++) {
      size_t key = (size_t)(kt * 32 + i);
      Ks[i][lane] = kbase[key * 2048 + lane];
      Vs[i][lane] = vbase[key * 1024 + lane];
    }
    __syncthreads();

#pragma unroll 2
    for (int j = 0; j < 32; j++) {
      float s0 = 0.f, s1 = 0.f, s2 = 0.f, s3 = 0.f;
#pragma unroll
      for (int d = 0; d < 64; d += 16) {
        float4 k0 = *(const float4*)&Ks[j][d];
        float4 k1 = *(const float4*)&Ks[j][d+4];
        float4 k2 = *(const float4*)&Ks[j][d+8];
        float4 k3 = *(const float4*)&Ks[j][d+12];
        s0 += qr[d+0]*k0.x + qr[d+1]*k0.y + qr[d+2]*k0.z + qr[d+3]*k0.w;
        s1 += qr[d+4]*k1.x + qr[d+5]*k1.y + qr[d+6]*k1.z + qr[d+7]*k1.w;
        s2 += qr[d+8]*k2.x + qr[d+9]*k2.y + qr[d+10]*k2.z + qr[d+11]*k2.w;
        s3 += qr[d+12]*k3.x + qr[d+13]*k3.y + qr[d+14]*k3.z + qr[d+15]*k3.w;
      }
      float s = ((s0 + s1) + (s2 + s3)) * 0.125f;   // 1/sqrt(64)
      float p;
      if (s > m) {
        float sc = __expf(m - s);     // first iter: exp(-inf) = 0
        lsum *= sc;
#pragma unroll
        for (int d = 0; d < 64; d++) acc[d] *= sc;
        m = s; p = 1.f;
      } else {
        p = __expf(s - m);
      }
      lsum += p;
#pragma unroll
      for (int d = 0; d < 64; d += 4) {
        float4 vv = *(const float4*)&Vs[j][d];
        acc[d+0] += p * vv.x; acc[d+1] += p * vv.y;
        acc[d+2] += p * vv.z; acc[d+3] += p * vv.w;
      }
    }
  }

  float invl = 1.f / lsum;
  float* orow = o + (size_t)row * 1024 + head * 64;
#pragma unroll
  for (int d4 = 0; d4 < 16; d4++) {
    float4 t;
    t.x = acc[d4*4+0] * invl; t.y = acc[d4*4+1] * invl;
    t.z = acc[d4*4+2] * invl; t.w = acc[d4*4+3] * invl;
    *(float4*)(orow + d4 * 4) = t;
  }
}

// ---------------------------------------------------------------------------
// x = LayerNorm(x + delta) * g + b   (in place on x; one block per row)
// ---------------------------------------------------------------------------
__global__ __launch_bounds__(256)
void add_ln_kernel(float* __restrict__ x, const float* __restrict__ d,
                   const float* __restrict__ g, const float* __restrict__ b)
{
  __shared__ float sb[4];
  const int row = blockIdx.x, tid = threadIdx.x;
  float* xr = x + (size_t)row * 1024;
  const float* dr = d + (size_t)row * 1024;

  float v[4]; float s = 0.f, ss = 0.f;
#pragma unroll
  for (int i = 0; i < 4; i++) {
    int c = tid + 256 * i;
    v[i] = xr[c] + dr[c];
    s += v[i]; ss += v[i] * v[i];
  }
#pragma unroll
  for (int off = 32; off; off >>= 1) { s += __shfl_down(s, off); ss += __shfl_down(ss, off); }
  const int lane = tid & 63, wid = tid >> 6;
  if (lane == 0) sb[wid] = s;
  __syncthreads();
  s = sb[0] + sb[1] + sb[2] + sb[3];
  __syncthreads();
  if (lane == 0) sb[wid] = ss;
  __syncthreads();
  ss = sb[0] + sb[1] + sb[2] + sb[3];

  float mean = s * (1.f / 1024.f);
  float var  = ss * (1.f / 1024.f) - mean * mean;
  float inv  = rsqrtf(var + 1e-5f);
#pragma unroll
  for (int i = 0; i < 4; i++) {
    int c = tid + 256 * i;
    xr[c] = (v[i] - mean) * inv * g[c] + b[c];
  }
}

// ---------------------------------------------------------------------------
// logits[u] = dot(h1[u], w2) + b2 -> fp32 into out[4097+u]
// One wave per row, 4 rows per block.
// ---------------------------------------------------------------------------
__global__ __launch_bounds__(256)
void logits_kernel(const float* __restrict__ h1, const float* __restrict__ w2,
                   const float* __restrict__ b2, float* __restrict__ out)
{
  const int lane = threadIdx.x & 63;
  const int row = blockIdx.x * 4 + (threadIdx.x >> 6);
  const float* hr = h1 + (size_t)row * 512;
  float s = 0.f;
#pragma unroll
  for (int i = 0; i < 8; i++) s += hr[lane + 64 * i] * w2[lane + 64 * i];
#pragma unroll
  for (int off = 32; off; off >>= 1) s += __shfl_down(s, off);
  if (lane == 0) {
    out[4097 + row] = s + b2[0];
  }
}

// ---------------------------------------------------------------------------
// probs = softmax(logits); entropy = -sum p*log(p+1e-12). Single block, 1024 thr.
// Reads fp32 logits from lg (= out+4097); writes probs -> out[0..4096),
// entropy -> out[4096]. All fp32.
// ---------------------------------------------------------------------------
__global__ __launch_bounds__(1024)
void softmax_entropy_kernel(const float* __restrict__ lg, float* __restrict__ out)
{
  __shared__ float sb[16];
  const int tid = threadIdx.x;
  const int lane = tid & 63, wid = tid >> 6;

  float l0[4];
#pragma unroll
  for (int i = 0; i < 4; i++) l0[i] = lg[tid + 1024 * i];

  float mx = fmaxf(fmaxf(l0[0], l0[1]), fmaxf(l0[2], l0[3]));
#pragma unroll
  for (int off = 32; off; off >>= 1) mx = fmaxf(mx, __shfl_down(mx, off));
  if (lane == 0) sb[wid] = mx;
  __syncthreads();
  if (tid == 0) { float m = sb[0]; for (int i = 1; i < 16; i++) m = fmaxf(m, sb[i]); sb[0] = m; }
  __syncthreads();
  mx = sb[0];
  __syncthreads();

  float e[4], s = 0.f;
#pragma unroll
  for (int i = 0; i < 4; i++) { e[i] = expf(l0[i] - mx); s += e[i]; }
#pragma unroll
  for (int off = 32; off; off >>= 1) s += __shfl_down(s, off);
  if (lane == 0) sb[wid] = s;
  __syncthreads();
  if (tid == 0) { float t = 0.f; for (int i = 0; i < 16; i++) t += sb[i]; sb[0] = t; }
  __syncthreads();
  float inv = 1.f / sb[0];
  __syncthreads();

  float h = 0.f;
#pragma unroll
  for (int i = 0; i < 4; i++) {
    float p = e[i] * inv;
    out[tid + 1024 * i] = p;
    h += p * logf(p + 1e-12f);
  }
#pragma unroll
  for (int off = 32; off; off >>= 1) h += __shfl_down(h, off);
  if (lane == 0) sb[wid] = h;
  __syncthreads();
  if (tid == 0) { float t = 0.f; for (int i = 0; i < 16; i++) t += sb[i]; out[4096] = -t; }
}

// ---------------------------------------------------------------------------
extern "C" void kernel_launch(void* const* d_in, const int* in_sizes, int n_in,
                              void* d_out, int out_size, void* d_ws, size_t ws_size,
                              hipStream_t stream)
{
  const float* node_emb   = (const float*)d_in[0];
  const int*   tile_ids   = (const int*)d_in[1];
  const float* entropies  = (const float*)d_in[2];
  const int*   Ny_p       = (const int*)d_in[3];
  const float* in_w       = (const float*)d_in[4];
  const float* in_b       = (const float*)d_in[5];
  const float* attn_in_w  = (const float*)d_in[6];
  const float* attn_in_b  = (const float*)d_in[7];
  const float* attn_out_w = (const float*)d_in[8];
  const float* attn_out_b = (const float*)d_in[9];
  const float* ff_w1      = (const float*)d_in[10];
  const float* ff_b1      = (const float*)d_in[11];
  const float* ff_w2      = (const float*)d_in[12];
  const float* ff_b2      = (const float*)d_in[13];
  const float* ln1_g      = (const float*)d_in[14];
  const float* ln1_b      = (const float*)d_in[15];
  const float* ln2_g      = (const float*)d_in[16];
  const float* ln2_b      = (const float*)d_in[17];
  const float* sh_w0      = (const float*)d_in[18];
  const float* sh_b0      = (const float*)d_in[19];
  const float* sh_w1      = (const float*)d_in[20];
  const float* sh_b1      = (const float*)d_in[21];
  const float* sh_w2      = (const float*)d_in[22];
  const float* sh_b2      = (const float*)d_in[23];
  float* out = (float*)d_out;    // reference outputs are float32

  // Workspace plan (floats). MF = 4M floats = 16 MB. Peak use: 16M floats (64 MB).
  float* ws = (float*)d_ws;
  const size_t MF = (size_t)UN * DN;      // 4194304
  float* X   = ws;                        // [0, MF)        x, persistent
  float* XR  = ws + MF;                   // [MF, 2MF)      rope(x); later o / f2 / h0,h1
  float* QK  = ws + 2 * MF;               // [2MF, 4MF)     fused q|k (ld 2048)
  float* V   = ws + 4 * MF;               // [4MF, 5MF)     v
  float* O   = XR;                        // attention output (xr dead)
  float* O2  = QK;                        // attn out-proj (qk dead after attention)
  float* Hb  = ws + 2 * MF;               // ffn hidden, 8M floats (o2 dead after LN1)
  float* F2  = XR;                        // ffn out (o dead)
  float* H0  = XR;                        // head hidden 0 (2M floats)
  float* H1  = XR + 2 * 1024 * 1024;      // head hidden 1 (2M floats)

  // x = [gather(node_emb, ids), entropies] @ in_w.T + in_b
  gemm_nt<<<dim3(32, 8), 256, 0, stream>>>(node_emb, in_w, in_b, X,
      1025, 1024, 1025, 1024, tile_ids, entropies, 0);

  for (int l = 0; l < LN_; l++) {
    const float* w_qkv = attn_in_w + (size_t)l * 3 * DN * DN;
    const float* b_qkv = attn_in_b + (size_t)l * 3 * DN;

    rope_kernel<<<UN * DN / 256, 256, 0, stream>>>(X, XR, tile_ids, Ny_p);
    // q|k from xr (N=2048 fused)
    gemm_nt<<<dim3(32, 16), 256, 0, stream>>>(XR, w_qkv, b_qkv, QK,
        1024, 1024, 1024, 2048, nullptr, nullptr, 0);
    // v from x
    gemm_nt<<<dim3(32, 8), 256, 0, stream>>>(X, w_qkv + (size_t)2048 * 1024, b_qkv + 2048, V,
        1024, 1024, 1024, 1024, nullptr, nullptr, 0);
    attn_kernel<<<dim3(UN / 64, HN), 64, 0, stream>>>(QK, V, O);
    gemm_nt<<<dim3(32, 8), 256, 0, stream>>>(O, attn_out_w + (size_t)l * DN * DN,
        attn_out_b + (size_t)l * DN, O2,
        1024, 1024, 1024, 1024, nullptr, nullptr, 0);
    add_ln_kernel<<<UN, 256, 0, stream>>>(X, O2, ln1_g + (size_t)l * DN, ln1_b + (size_t)l * DN);
    gemm_nt<<<dim3(32, 16), 256, 0, stream>>>(X, ff_w1 + (size_t)l * 2 * DN * DN,
        ff_b1 + (size_t)l * 2 * DN, Hb,
        1024, 1024, 1024, 2048, nullptr, nullptr, 1);
    gemm_nt<<<dim3(32, 8), 256, 0, stream>>>(Hb, ff_w2 + (size_t)l * DN * 2 * DN,
        ff_b2 + (size_t)l * DN, F2,
        2048, 2048, 2048, 1024, nullptr, nullptr, 0);
    add_ln_kernel<<<UN, 256, 0, stream>>>(X, F2, ln2_g + (size_t)l * DN, ln2_b + (size_t)l * DN);
  }

  // head MLP
  gemm_nt<<<dim3(32, 4), 256, 0, stream>>>(X, sh_w0, sh_b0, H0,
      1024, 1024, 1024, 512, nullptr, nullptr, 1);
  gemm_nt<<<dim3(32, 4), 256, 0, stream>>>(H0, sh_w1, sh_b1, H1,
      512, 512, 512, 512, nullptr, nullptr, 1);
  logits_kernel<<<UN / 4, 256, 0, stream>>>(H1, sh_w2, sh_b2, out);
  softmax_entropy_kernel<<<1, 1024, 0, stream>>>(out + 4097, out);
}

// Round 3
// 6455.211 us; speedup vs baseline: 3.2170x; 3.2170x over previous
//
#include <hip/hip_runtime.h>
#include <hip/hip_bf16.h>
#include <math.h>

// Problem constants
#define UN 4096      // units
#define DN 1024      // model dim
#define LN_ 4        // layers
#define HN 16        // heads
#define HD 64        // head dim
#define HIDN 512     // head MLP hidden

typedef __attribute__((ext_vector_type(8))) short bf16x8;   // 8 bf16 = 4 VGPRs
typedef __attribute__((ext_vector_type(4))) float f32x4;

// float -> bf16 bits, round-to-nearest-even
__device__ __forceinline__ short f2bf(float f) {
  union { float f; unsigned u; } x; x.f = f;
  unsigned r = x.u + 0x7fffu + ((x.u >> 16) & 1u);
  return (short)(r >> 16);
}

// ---------------------------------------------------------------------------
// Generic fp32 GEMM:  C[m][n] = act( sum_k A[m][k] * W[n][k] + bias[n] )
// (unchanged from round 2 — known good)
// ---------------------------------------------------------------------------
__global__ __launch_bounds__(256)
void gemm_nt(const float* __restrict__ A, const float* __restrict__ W,
             const float* __restrict__ bias, float* __restrict__ C,
             int K, int lda, int ldw, int ldc,
             const int* __restrict__ ids, const float* __restrict__ ent,
             int relu)
{
  __shared__ __align__(16) float As[16][132];
  __shared__ __align__(16) float Ws[16][132];

  const int tid = threadIdx.x;
  const int bm = blockIdx.x, bn = blockIdx.y;
  const int ty = tid >> 4, tx = tid & 15;

  float acc[8][8];
#pragma unroll
  for (int i = 0; i < 8; i++)
#pragma unroll
    for (int j = 0; j < 8; j++) acc[i][j] = 0.f;

  const int srow = tid >> 1;
  const int sk   = (tid & 1) * 8;
  const int ga   = bm * 128 + srow;
  const float* abase = ids ? (A + (size_t)ids[ga] * lda)
                           : (A + (size_t)ga * lda);
  const int gw = bn * 128 + srow;
  const float* wbase = W + (size_t)gw * ldw;
  const bool wvec = ((ldw & 3) == 0);
  const int kA = ids ? lda : K;

  for (int kk = 0; kk < K; kk += 16) {
    const int k0 = kk + sk;
    float av[8], wv[8];
    if (k0 + 8 <= kA) {
      float4 p0 = *(const float4*)(abase + k0);
      float4 p1 = *(const float4*)(abase + k0 + 4);
      av[0]=p0.x; av[1]=p0.y; av[2]=p0.z; av[3]=p0.w;
      av[4]=p1.x; av[5]=p1.y; av[6]=p1.z; av[7]=p1.w;
    } else {
#pragma unroll
      for (int i = 0; i < 8; i++) {
        int k = k0 + i; float v = 0.f;
        if (k < kA) v = abase[k];
        else if (ids && k == lda && k < K) v = ent[ga];
        av[i] = v;
      }
    }
    if (wvec && (k0 + 8 <= K)) {
      float4 p0 = *(const float4*)(wbase + k0);
      float4 p1 = *(const float4*)(wbase + k0 + 4);
      wv[0]=p0.x; wv[1]=p0.y; wv[2]=p0.z; wv[3]=p0.w;
      wv[4]=p1.x; wv[5]=p1.y; wv[6]=p1.z; wv[7]=p1.w;
    } else {
#pragma unroll
      for (int i = 0; i < 8; i++) { int k = k0 + i; wv[i] = (k < K) ? wbase[k] : 0.f; }
    }

    __syncthreads();
#pragma unroll
    for (int i = 0; i < 8; i++) As[sk + i][srow] = av[i];
#pragma unroll
    for (int i = 0; i < 8; i++) Ws[sk + i][srow] = wv[i];
    __syncthreads();

#pragma unroll 4
    for (int k = 0; k < 16; k++) {
      float4 a0 = *(const float4*)&As[k][ty * 8];
      float4 a1 = *(const float4*)&As[k][ty * 8 + 4];
      float4 b0 = *(const float4*)&Ws[k][tx * 8];
      float4 b1 = *(const float4*)&Ws[k][tx * 8 + 4];
      float a[8]  = {a0.x,a0.y,a0.z,a0.w,a1.x,a1.y,a1.z,a1.w};
      float bb[8] = {b0.x,b0.y,b0.z,b0.w,b1.x,b1.y,b1.z,b1.w};
#pragma unroll
      for (int i = 0; i < 8; i++)
#pragma unroll
        for (int j = 0; j < 8; j++)
          acc[i][j] += a[i] * bb[j];
    }
  }

  const int col0 = bn * 128 + tx * 8;
#pragma unroll
  for (int i = 0; i < 8; i++) {
    const int row = bm * 128 + ty * 8 + i;
    float* crow = C + (size_t)row * ldc + col0;
#pragma unroll
    for (int j = 0; j < 8; j += 4) {
      float v0 = acc[i][j+0] + bias[col0+j+0];
      float v1 = acc[i][j+1] + bias[col0+j+1];
      float v2 = acc[i][j+2] + bias[col0+j+2];
      float v3 = acc[i][j+3] + bias[col0+j+3];
      if (relu) { v0=fmaxf(v0,0.f); v1=fmaxf(v1,0.f); v2=fmaxf(v2,0.f); v3=fmaxf(v3,0.f); }
      float4 r; r.x=v0; r.y=v1; r.z=v2; r.w=v3;
      *(float4*)(crow + j) = r;
    }
  }
}

// ---------------------------------------------------------------------------
// RoPE (unchanged)
// ---------------------------------------------------------------------------
__global__ __launch_bounds__(256)
void rope_kernel(const float* __restrict__ x, float* __restrict__ xr,
                 const int* __restrict__ ids, const int* __restrict__ nyp)
{
  int idx = blockIdx.x * 256 + threadIdx.x;
  int u = idx >> 10, j = idx & 1023;
  int blk = j >> 9, o = j & 511;
  int i = o & 255;
  int t = ids[u];
  int ny = *nyp;
  float pos = (blk == 0) ? (float)(t / ny) : (float)(t % ny);
  float theta = expf((float)i * -0.0359778921f);
  float ang = pos * theta;
  float c = cosf(ang), sn = sinf(ang);
  const float* xrow = x + (size_t)u * 1024 + blk * 512;
  float x1 = xrow[i];
  float x2 = xrow[256 + i];
  xr[idx] = (o < 256) ? (x1 * c - x2 * sn) : (x1 * sn + x2 * c);
}

// ---------------------------------------------------------------------------
// MFMA bf16 flash attention. 4096 keys, hd=64, 16 heads.
// Workgroup = 256 thr (4 waves); Q-block = 64 rows (16 rows/wave).
// K-tile = 64 keys, staged in LDS: Kt[key][d] row-major, Vt[d][key] transposed,
// both bf16, leading dim 72 (uniform LDS bank usage for b128 frag reads).
// QK^T and PV via mfma_f32_16x16x32_bf16; online softmax in C-layout regs;
// P round-trips LDS (C-layout -> A-layout, per-wave slab).
// Q frags: A[m=lane&15][k=quad*8+j]; scale 1/8 folded into Q (exact pow2).
// ---------------------------------------------------------------------------
__global__ __launch_bounds__(256)
void attn_mfma_kernel(const float* __restrict__ qk, const float* __restrict__ v,
                      float* __restrict__ o)
{
  __shared__ __align__(16) short Kt[64][72];
  __shared__ __align__(16) short Vt[64][72];      // [d][key]
  __shared__ __align__(16) short Pb[4][16][72];   // per-wave P slab

  const int tid  = threadIdx.x;
  const int lane = tid & 63;
  const int wave = tid >> 6;
  const int head = blockIdx.y;
  const int qb   = blockIdx.x;

  const int n    = lane & 15;
  const int quad = lane >> 4;

  // Q fragments (held for whole kernel): row = qb*64 + wave*16 + n
  bf16x8 qfrag[2];
  {
    const int qrow = qb * 64 + wave * 16 + n;
    const float* qptr = qk + (size_t)qrow * 2048 + head * 64 + quad * 8;
#pragma unroll
    for (int c = 0; c < 2; c++)
#pragma unroll
      for (int j = 0; j < 8; j++)
        qfrag[c][j] = f2bf(qptr[c * 32 + j] * 0.125f);
  }

  float m_r[4], l_r[4];
  f32x4 o_acc[4];
#pragma unroll
  for (int r = 0; r < 4; r++) { m_r[r] = -3.0e38f; l_r[r] = 0.f; }
#pragma unroll
  for (int nb = 0; nb < 4; nb++)
#pragma unroll
    for (int r = 0; r < 4; r++) o_acc[nb][r] = 0.f;

  const int skey = tid & 63;          // staging: key row
  const int sd0  = (tid >> 6) * 16;   // staging: d-chunk

  for (int kt = 0; kt < 64; kt++) {
    __syncthreads();
    // ---- stage K (row-major) and V (transposed) as bf16 ----
    {
      const float* kp = qk + (size_t)(kt * 64 + skey) * 2048 + 1024 + head * 64 + sd0;
      bf16x8 kb0, kb1;
#pragma unroll
      for (int j = 0; j < 8; j++) { kb0[j] = f2bf(kp[j]); kb1[j] = f2bf(kp[8 + j]); }
      *(bf16x8*)&Kt[skey][sd0]     = kb0;
      *(bf16x8*)&Kt[skey][sd0 + 8] = kb1;
      const float* vp = v + (size_t)(kt * 64 + skey) * 1024 + head * 64 + sd0;
#pragma unroll
      for (int i = 0; i < 16; i++) Vt[sd0 + i][skey] = f2bf(vp[i]);
    }
    __syncthreads();

    // ---- QK^T: S[16 q][64 keys] ----
    f32x4 s[4];
#pragma unroll
    for (int nb = 0; nb < 4; nb++) {
      bf16x8 k0 = *(bf16x8*)&Kt[nb * 16 + n][quad * 8];
      bf16x8 k1 = *(bf16x8*)&Kt[nb * 16 + n][32 + quad * 8];
      f32x4 z = {0.f, 0.f, 0.f, 0.f};
      z = __builtin_amdgcn_mfma_f32_16x16x32_bf16(qfrag[0], k0, z, 0, 0, 0);
      z = __builtin_amdgcn_mfma_f32_16x16x32_bf16(qfrag[1], k1, z, 0, 0, 0);
      s[nb] = z;
    }

    // ---- online softmax (row = quad*4 + r; 16 cols spread over lanes n) ----
    float al[4], rs[4];
#pragma unroll
    for (int r = 0; r < 4; r++) {
      float t = fmaxf(fmaxf(s[0][r], s[1][r]), fmaxf(s[2][r], s[3][r]));
      t = fmaxf(t, __shfl_xor(t, 1));
      t = fmaxf(t, __shfl_xor(t, 2));
      t = fmaxf(t, __shfl_xor(t, 4));
      t = fmaxf(t, __shfl_xor(t, 8));
      float mnew = fmaxf(m_r[r], t);
      al[r] = __expf(m_r[r] - mnew);
      m_r[r] = mnew;
      rs[r] = 0.f;
    }
    short pbits[4][4];
#pragma unroll
    for (int nb = 0; nb < 4; nb++)
#pragma unroll
      for (int r = 0; r < 4; r++) {
        float p = __expf(s[nb][r] - m_r[r]);
        rs[r] += p;
        pbits[nb][r] = f2bf(p);
      }
#pragma unroll
    for (int r = 0; r < 4; r++) {
      float t = rs[r];
      t += __shfl_xor(t, 1); t += __shfl_xor(t, 2);
      t += __shfl_xor(t, 4); t += __shfl_xor(t, 8);
      l_r[r] = l_r[r] * al[r] + t;
    }
    // P -> per-wave LDS slab (C-layout write)
#pragma unroll
    for (int nb = 0; nb < 4; nb++)
#pragma unroll
      for (int r = 0; r < 4; r++)
        Pb[wave][quad * 4 + r][nb * 16 + n] = pbits[nb][r];
    // rescale O
#pragma unroll
    for (int nb = 0; nb < 4; nb++)
#pragma unroll
      for (int r = 0; r < 4; r++) o_acc[nb][r] *= al[r];

    // ---- PV: O += P · V ----
#pragma unroll
    for (int c = 0; c < 2; c++) {
      bf16x8 pf = *(bf16x8*)&Pb[wave][n][c * 32 + quad * 8];
#pragma unroll
      for (int nb = 0; nb < 4; nb++) {
        bf16x8 vf = *(bf16x8*)&Vt[nb * 16 + n][c * 32 + quad * 8];
        o_acc[nb] = __builtin_amdgcn_mfma_f32_16x16x32_bf16(pf, vf, o_acc[nb], 0, 0, 0);
      }
    }
  }

  // epilogue: O /= l, write (C-layout rows)
#pragma unroll
  for (int r = 0; r < 4; r++) l_r[r] = 1.f / l_r[r];
#pragma unroll
  for (int nb = 0; nb < 4; nb++)
#pragma unroll
    for (int r = 0; r < 4; r++) {
      int row = qb * 64 + wave * 16 + quad * 4 + r;
      o[(size_t)row * 1024 + head * 64 + nb * 16 + n] = o_acc[nb][r] * l_r[r];
    }
}

// ---------------------------------------------------------------------------
// x = LayerNorm(x + delta) * g + b   (unchanged)
// ---------------------------------------------------------------------------
__global__ __launch_bounds__(256)
void add_ln_kernel(float* __restrict__ x, const float* __restrict__ d,
                   const float* __restrict__ g, const float* __restrict__ b)
{
  __shared__ float sb[4];
  const int row = blockIdx.x, tid = threadIdx.x;
  float* xr = x + (size_t)row * 1024;
  const float* dr = d + (size_t)row * 1024;

  float v[4]; float s = 0.f, ss = 0.f;
#pragma unroll
  for (int i = 0; i < 4; i++) {
    int c = tid + 256 * i;
    v[i] = xr[c] + dr[c];
    s += v[i]; ss += v[i] * v[i];
  }
#pragma unroll
  for (int off = 32; off; off >>= 1) { s += __shfl_down(s, off); ss += __shfl_down(ss, off); }
  const int lane = tid & 63, wid = tid >> 6;
  if (lane == 0) sb[wid] = s;
  __syncthreads();
  s = sb[0] + sb[1] + sb[2] + sb[3];
  __syncthreads();
  if (lane == 0) sb[wid] = ss;
  __syncthreads();
  ss = sb[0] + sb[1] + sb[2] + sb[3];

  float mean = s * (1.f / 1024.f);
  float var  = ss * (1.f / 1024.f) - mean * mean;
  float inv  = rsqrtf(var + 1e-5f);
#pragma unroll
  for (int i = 0; i < 4; i++) {
    int c = tid + 256 * i;
    xr[c] = (v[i] - mean) * inv * g[c] + b[c];
  }
}

// ---------------------------------------------------------------------------
// logits + softmax/entropy (unchanged)
// ---------------------------------------------------------------------------
__global__ __launch_bounds__(256)
void logits_kernel(const float* __restrict__ h1, const float* __restrict__ w2,
                   const float* __restrict__ b2, float* __restrict__ out)
{
  const int lane = threadIdx.x & 63;
  const int row = blockIdx.x * 4 + (threadIdx.x >> 6);
  const float* hr = h1 + (size_t)row * 512;
  float s = 0.f;
#pragma unroll
  for (int i = 0; i < 8; i++) s += hr[lane + 64 * i] * w2[lane + 64 * i];
#pragma unroll
  for (int off = 32; off; off >>= 1) s += __shfl_down(s, off);
  if (lane == 0) {
    out[4097 + row] = s + b2[0];
  }
}

__global__ __launch_bounds__(1024)
void softmax_entropy_kernel(const float* __restrict__ lg, float* __restrict__ out)
{
  __shared__ float sb[16];
  const int tid = threadIdx.x;
  const int lane = tid & 63, wid = tid >> 6;

  float l0[4];
#pragma unroll
  for (int i = 0; i < 4; i++) l0[i] = lg[tid + 1024 * i];

  float mx = fmaxf(fmaxf(l0[0], l0[1]), fmaxf(l0[2], l0[3]));
#pragma unroll
  for (int off = 32; off; off >>= 1) mx = fmaxf(mx, __shfl_down(mx, off));
  if (lane == 0) sb[wid] = mx;
  __syncthreads();
  if (tid == 0) { float m = sb[0]; for (int i = 1; i < 16; i++) m = fmaxf(m, sb[i]); sb[0] = m; }
  __syncthreads();
  mx = sb[0];
  __syncthreads();

  float e[4], s = 0.f;
#pragma unroll
  for (int i = 0; i < 4; i++) { e[i] = expf(l0[i] - mx); s += e[i]; }
#pragma unroll
  for (int off = 32; off; off >>= 1) s += __shfl_down(s, off);
  if (lane == 0) sb[wid] = s;
  __syncthreads();
  if (tid == 0) { float t = 0.f; for (int i = 0; i < 16; i++) t += sb[i]; sb[0] = t; }
  __syncthreads();
  float inv = 1.f / sb[0];
  __syncthreads();

  float h = 0.f;
#pragma unroll
  for (int i = 0; i < 4; i++) {
    float p = e[i] * inv;
    out[tid + 1024 * i] = p;
    h += p * logf(p + 1e-12f);
  }
#pragma unroll
  for (int off = 32; off; off >>= 1) h += __shfl_down(h, off);
  if (lane == 0) sb[wid] = h;
  __syncthreads();
  if (tid == 0) { float t = 0.f; for (int i = 0; i < 16; i++) t += sb[i]; out[4096] = -t; }
}

// ---------------------------------------------------------------------------
extern "C" void kernel_launch(void* const* d_in, const int* in_sizes, int n_in,
                              void* d_out, int out_size, void* d_ws, size_t ws_size,
                              hipStream_t stream)
{
  const float* node_emb   = (const float*)d_in[0];
  const int*   tile_ids   = (const int*)d_in[1];
  const float* entropies  = (const float*)d_in[2];
  const int*   Ny_p       = (const int*)d_in[3];
  const float* in_w       = (const float*)d_in[4];
  const float* in_b       = (const float*)d_in[5];
  const float* attn_in_w  = (const float*)d_in[6];
  const float* attn_in_b  = (const float*)d_in[7];
  const float* attn_out_w = (const float*)d_in[8];
  const float* attn_out_b = (const float*)d_in[9];
  const float* ff_w1      = (const float*)d_in[10];
  const float* ff_b1      = (const float*)d_in[11];
  const float* ff_w2      = (const float*)d_in[12];
  const float* ff_b2      = (const float*)d_in[13];
  const float* ln1_g      = (const float*)d_in[14];
  const float* ln1_b      = (const float*)d_in[15];
  const float* ln2_g      = (const float*)d_in[16];
  const float* ln2_b      = (const float*)d_in[17];
  const float* sh_w0      = (const float*)d_in[18];
  const float* sh_b0      = (const float*)d_in[19];
  const float* sh_w1      = (const float*)d_in[20];
  const float* sh_b1      = (const float*)d_in[21];
  const float* sh_w2      = (const float*)d_in[22];
  const float* sh_b2      = (const float*)d_in[23];
  float* out = (float*)d_out;

  float* ws = (float*)d_ws;
  const size_t MF = (size_t)UN * DN;      // 4194304
  float* X   = ws;                        // x, persistent
  float* XR  = ws + MF;                   // rope(x); later o / f2 / h0,h1
  float* QK  = ws + 2 * MF;               // fused q|k (ld 2048)
  float* V   = ws + 4 * MF;               // v
  float* O   = XR;
  float* O2  = QK;
  float* Hb  = ws + 2 * MF;
  float* F2  = XR;
  float* H0  = XR;
  float* H1  = XR + 2 * 1024 * 1024;

  gemm_nt<<<dim3(32, 8), 256, 0, stream>>>(node_emb, in_w, in_b, X,
      1025, 1024, 1025, 1024, tile_ids, entropies, 0);

  for (int l = 0; l < LN_; l++) {
    const float* w_qkv = attn_in_w + (size_t)l * 3 * DN * DN;
    const float* b_qkv = attn_in_b + (size_t)l * 3 * DN;

    rope_kernel<<<UN * DN / 256, 256, 0, stream>>>(X, XR, tile_ids, Ny_p);
    gemm_nt<<<dim3(32, 16), 256, 0, stream>>>(XR, w_qkv, b_qkv, QK,
        1024, 1024, 1024, 2048, nullptr, nullptr, 0);
    gemm_nt<<<dim3(32, 8), 256, 0, stream>>>(X, w_qkv + (size_t)2048 * 1024, b_qkv + 2048, V,
        1024, 1024, 1024, 1024, nullptr, nullptr, 0);
    attn_mfma_kernel<<<dim3(UN / 64, HN), 256, 0, stream>>>(QK, V, O);
    gemm_nt<<<dim3(32, 8), 256, 0, stream>>>(O, attn_out_w + (size_t)l * DN * DN,
        attn_out_b + (size_t)l * DN, O2,
        1024, 1024, 1024, 1024, nullptr, nullptr, 0);
    add_ln_kernel<<<UN, 256, 0, stream>>>(X, O2, ln1_g + (size_t)l * DN, ln1_b + (size_t)l * DN);
    gemm_nt<<<dim3(32, 16), 256, 0, stream>>>(X, ff_w1 + (size_t)l * 2 * DN * DN,
        ff_b1 + (size_t)l * 2 * DN, Hb,
        1024, 1024, 1024, 2048, nullptr, nullptr, 1);
    gemm_nt<<<dim3(32, 8), 256, 0, stream>>>(Hb, ff_w2 + (size_t)l * DN * 2 * DN,
        ff_b2 + (size_t)l * DN, F2,
        2048, 2048, 2048, 1024, nullptr, nullptr, 0);
    add_ln_kernel<<<UN, 256, 0, stream>>>(X, F2, ln2_g + (size_t)l * DN, ln2_b + (size_t)l * DN);
  }

  gemm_nt<<<dim3(32, 4), 256, 0, stream>>>(X, sh_w0, sh_b0, H0,
      1024, 1024, 1024, 512, nullptr, nullptr, 1);
  gemm_nt<<<dim3(32, 4), 256, 0, stream>>>(H0, sh_w1, sh_b1, H1,
      512, 512, 512, 512, nullptr, nullptr, 1);
  logits_kernel<<<UN / 4, 256, 0, stream>>>(H1, sh_w2, sh_b2, out);
  softmax_entropy_kernel<<<1, 1024, 0, stream>>>(out + 4097, out);
}

// Round 4
// 2820.475 us; speedup vs baseline: 7.3627x; 2.2887x over previous
//
#include <hip/hip_runtime.h>
#include <hip/hip_bf16.h>
#include <math.h>

// Problem constants
#define UN 4096      // units
#define DN 1024      // model dim
#define LN_ 4        // layers
#define HN 16        // heads
#define HD 64        // head dim

typedef __attribute__((ext_vector_type(8))) short bf16x8;   // 8 bf16 = 4 VGPRs
typedef __attribute__((ext_vector_type(4))) float f32x4;

// float -> bf16 bits, round-to-nearest-even
__device__ __forceinline__ short f2bf(float f) {
  union { float f; unsigned u; } x; x.f = f;
  unsigned r = x.u + 0x7fffu + ((x.u >> 16) & 1u);
  return (short)(r >> 16);
}
__device__ __forceinline__ float bf2f(short b) {
  union { unsigned u; float f; } x; x.u = ((unsigned)(unsigned short)b) << 16;
  return x.f;
}

// ---------------------------------------------------------------------------
// bf16 MFMA GEMM:  C[m][n] = act( sum_k A[m][k]*W[n][k] + bias[n] [+ ent[m]*wcol[n]] )
// A: M x K bf16 (lda). W: N x K fp32 (ldw) — converted to bf16 during staging.
//   (scalar W loads when ldw%4 != 0, i.e. GEMM0's ldw=1025)
// C32 / C16: optional fp32 / bf16 outputs (ldc).
// ent/wcol: optional rank-1 update (GEMM0 entropy column), wcol stride = wstride.
// Tile 128x128, BK=32, 256 thr = 4 waves (2x2 of 64x64), 4x4 MFMA 16x16x32 each.
// M%128==0, N%128==0, K%32==0 for every call.
// ---------------------------------------------------------------------------
__global__ __launch_bounds__(256)
void gemm_bf16(const short* __restrict__ A, int lda,
               const float* __restrict__ W, int ldw,
               const float* __restrict__ bias,
               float* __restrict__ C32, short* __restrict__ C16, int ldc,
               int K, int relu,
               const float* __restrict__ ent, const float* __restrict__ wcol,
               int wstride)
{
  __shared__ __align__(16) short As[128][40];   // ld 40 shorts = 80 B (16B-aligned rows)
  __shared__ __align__(16) short Ws[128][40];

  const int tid  = threadIdx.x;
  const int bm = blockIdx.x, bn = blockIdx.y;
  const int lane = tid & 63, wave = tid >> 6;
  const int n = lane & 15, quad = lane >> 4;
  const int mw = (wave >> 1) * 64, nw = (wave & 1) * 64;

  f32x4 acc[4][4];
#pragma unroll
  for (int mb = 0; mb < 4; mb++)
#pragma unroll
    for (int nb = 0; nb < 4; nb++)
#pragma unroll
      for (int r = 0; r < 4; r++) acc[mb][nb][r] = 0.f;

  const int srow = tid >> 1;            // staging row (A-row / W-row within tile)
  const int skh  = (tid & 1) * 16;      // k-half offset
  const short* aptr = A + (size_t)(bm * 128 + srow) * lda + skh;
  const float* wptr = W + (size_t)(bn * 128 + srow) * ldw + skh;
  const bool wal = ((ldw & 3) == 0);

  for (int kk = 0; kk < K; kk += 32) {
    // ---- global loads ----
    bf16x8 a0 = *(const bf16x8*)(aptr + kk);
    bf16x8 a1 = *(const bf16x8*)(aptr + kk + 8);
    bf16x8 w0, w1;
    if (wal) {
      float4 f0 = *(const float4*)(wptr + kk);
      float4 f1 = *(const float4*)(wptr + kk + 4);
      float4 f2 = *(const float4*)(wptr + kk + 8);
      float4 f3 = *(const float4*)(wptr + kk + 12);
      w0[0]=f2bf(f0.x); w0[1]=f2bf(f0.y); w0[2]=f2bf(f0.z); w0[3]=f2bf(f0.w);
      w0[4]=f2bf(f1.x); w0[5]=f2bf(f1.y); w0[6]=f2bf(f1.z); w0[7]=f2bf(f1.w);
      w1[0]=f2bf(f2.x); w1[1]=f2bf(f2.y); w1[2]=f2bf(f2.z); w1[3]=f2bf(f2.w);
      w1[4]=f2bf(f3.x); w1[5]=f2bf(f3.y); w1[6]=f2bf(f3.z); w1[7]=f2bf(f3.w);
    } else {
#pragma unroll
      for (int j = 0; j < 8; j++) w0[j] = f2bf(wptr[kk + j]);
#pragma unroll
      for (int j = 0; j < 8; j++) w1[j] = f2bf(wptr[kk + 8 + j]);
    }

    __syncthreads();    // previous tile's frag reads done
    *(bf16x8*)&As[srow][skh]     = a0;
    *(bf16x8*)&As[srow][skh + 8] = a1;
    *(bf16x8*)&Ws[srow][skh]     = w0;
    *(bf16x8*)&Ws[srow][skh + 8] = w1;
    __syncthreads();

    bf16x8 af[4], bfr[4];
#pragma unroll
    for (int mb = 0; mb < 4; mb++) af[mb] = *(bf16x8*)&As[mw + mb * 16 + n][quad * 8];
#pragma unroll
    for (int nb = 0; nb < 4; nb++) bfr[nb] = *(bf16x8*)&Ws[nw + nb * 16 + n][quad * 8];
#pragma unroll
    for (int mb = 0; mb < 4; mb++)
#pragma unroll
      for (int nb = 0; nb < 4; nb++)
        acc[mb][nb] = __builtin_amdgcn_mfma_f32_16x16x32_bf16(af[mb], bfr[nb], acc[mb][nb], 0, 0, 0);
  }

  // ---- epilogue (MFMA C-layout: row = quad*4+r, col = n within 16x16) ----
#pragma unroll
  for (int mb = 0; mb < 4; mb++) {
    float entv[4];
#pragma unroll
    for (int r = 0; r < 4; r++)
      entv[r] = ent ? ent[bm * 128 + mw + mb * 16 + quad * 4 + r] : 0.f;
#pragma unroll
    for (int nb = 0; nb < 4; nb++) {
      const int col = bn * 128 + nw + nb * 16 + n;
      const float bs = bias[col];
      const float wc = ent ? wcol[(size_t)col * wstride] : 0.f;
#pragma unroll
      for (int r = 0; r < 4; r++) {
        const int row = bm * 128 + mw + mb * 16 + quad * 4 + r;
        float v = acc[mb][nb][r] + bs;
        if (ent)  v += entv[r] * wc;
        if (relu) v = fmaxf(v, 0.f);
        if (C32) C32[(size_t)row * ldc + col] = v;
        if (C16) C16[(size_t)row * ldc + col] = f2bf(v);
      }
    }
  }
}

// ---------------------------------------------------------------------------
// gather + fp32->bf16: dst[u][k] = bf16(node_emb[ids[u]][k])
// ---------------------------------------------------------------------------
__global__ __launch_bounds__(256)
void gather_conv_kernel(const float* __restrict__ emb, const int* __restrict__ ids,
                        short* __restrict__ dst)
{
  int idx = blockIdx.x * 256 + threadIdx.x;   // < UN*DN
  int u = idx >> 10;
  dst[idx] = f2bf(emb[(size_t)ids[u] * 1024 + (idx & 1023)]);
}

// ---------------------------------------------------------------------------
// RoPE: reads X fp32, writes bf16 xr
// ---------------------------------------------------------------------------
__global__ __launch_bounds__(256)
void rope_kernel(const float* __restrict__ x, short* __restrict__ xr,
                 const int* __restrict__ ids, const int* __restrict__ nyp)
{
  int idx = blockIdx.x * 256 + threadIdx.x;
  int u = idx >> 10, j = idx & 1023;
  int blk = j >> 9, o = j & 511;
  int i = o & 255;
  int t = ids[u];
  int ny = *nyp;
  float pos = (blk == 0) ? (float)(t / ny) : (float)(t % ny);
  float theta = expf((float)i * -0.0359778921f);   // -ln(10000)/256
  float ang = pos * theta;
  float c = cosf(ang), sn = sinf(ang);
  const float* xrow = x + (size_t)u * 1024 + blk * 512;
  float x1 = xrow[i];
  float x2 = xrow[256 + i];
  xr[idx] = f2bf((o < 256) ? (x1 * c - x2 * sn) : (x1 * sn + x2 * c));
}

// ---------------------------------------------------------------------------
// MFMA bf16 flash attention (bf16 in / bf16 out).
// qk: bf16 [4096][2048] fused q|k; v: bf16 [4096][1024]; o: bf16 [4096][1024].
// Same structure as round 3 (verified correct), minus fp32->bf16 conversions.
// ---------------------------------------------------------------------------
__global__ __launch_bounds__(256)
void attn_mfma_kernel(const short* __restrict__ qk, const short* __restrict__ v,
                      short* __restrict__ o)
{
  __shared__ __align__(16) short Kt[64][72];
  __shared__ __align__(16) short Vt[64][72];      // [d][key]
  __shared__ __align__(16) short Pb[4][16][72];   // per-wave P slab

  const int tid  = threadIdx.x;
  const int lane = tid & 63;
  const int wave = tid >> 6;
  const int head = blockIdx.y;
  const int qb   = blockIdx.x;

  const int n    = lane & 15;
  const int quad = lane >> 4;

  // Q fragments: row = qb*64 + wave*16 + n ; scale 1/8 exact (pow2)
  bf16x8 qfrag[2];
  {
    const int qrow = qb * 64 + wave * 16 + n;
    const short* qptr = qk + (size_t)qrow * 2048 + head * 64 + quad * 8;
#pragma unroll
    for (int c = 0; c < 2; c++)
#pragma unroll
      for (int j = 0; j < 8; j++)
        qfrag[c][j] = f2bf(bf2f(qptr[c * 32 + j]) * 0.125f);
  }

  float m_r[4], l_r[4];
  f32x4 o_acc[4];
#pragma unroll
  for (int r = 0; r < 4; r++) { m_r[r] = -3.0e38f; l_r[r] = 0.f; }
#pragma unroll
  for (int nb = 0; nb < 4; nb++)
#pragma unroll
    for (int r = 0; r < 4; r++) o_acc[nb][r] = 0.f;

  const int skey = tid & 63;          // staging: key row
  const int sd0  = (tid >> 6) * 16;   // staging: d-chunk

  for (int kt = 0; kt < 64; kt++) {
    __syncthreads();
    {
      const short* kp = qk + (size_t)(kt * 64 + skey) * 2048 + 1024 + head * 64 + sd0;
      *(bf16x8*)&Kt[skey][sd0]     = *(const bf16x8*)(kp);
      *(bf16x8*)&Kt[skey][sd0 + 8] = *(const bf16x8*)(kp + 8);
      const short* vp = v + (size_t)(kt * 64 + skey) * 1024 + head * 64 + sd0;
#pragma unroll
      for (int i = 0; i < 16; i++) Vt[sd0 + i][skey] = vp[i];
    }
    __syncthreads();

    // ---- QK^T ----
    f32x4 s[4];
#pragma unroll
    for (int nb = 0; nb < 4; nb++) {
      bf16x8 k0 = *(bf16x8*)&Kt[nb * 16 + n][quad * 8];
      bf16x8 k1 = *(bf16x8*)&Kt[nb * 16 + n][32 + quad * 8];
      f32x4 z = {0.f, 0.f, 0.f, 0.f};
      z = __builtin_amdgcn_mfma_f32_16x16x32_bf16(qfrag[0], k0, z, 0, 0, 0);
      z = __builtin_amdgcn_mfma_f32_16x16x32_bf16(qfrag[1], k1, z, 0, 0, 0);
      s[nb] = z;
    }

    // ---- online softmax ----
    float al[4], rs[4];
#pragma unroll
    for (int r = 0; r < 4; r++) {
      float t = fmaxf(fmaxf(s[0][r], s[1][r]), fmaxf(s[2][r], s[3][r]));
      t = fmaxf(t, __shfl_xor(t, 1));
      t = fmaxf(t, __shfl_xor(t, 2));
      t = fmaxf(t, __shfl_xor(t, 4));
      t = fmaxf(t, __shfl_xor(t, 8));
      float mnew = fmaxf(m_r[r], t);
      al[r] = __expf(m_r[r] - mnew);
      m_r[r] = mnew;
      rs[r] = 0.f;
    }
    short pbits[4][4];
#pragma unroll
    for (int nb = 0; nb < 4; nb++)
#pragma unroll
      for (int r = 0; r < 4; r++) {
        float p = __expf(s[nb][r] - m_r[r]);
        rs[r] += p;
        pbits[nb][r] = f2bf(p);
      }
#pragma unroll
    for (int r = 0; r < 4; r++) {
      float t = rs[r];
      t += __shfl_xor(t, 1); t += __shfl_xor(t, 2);
      t += __shfl_xor(t, 4); t += __shfl_xor(t, 8);
      l_r[r] = l_r[r] * al[r] + t;
    }
#pragma unroll
    for (int nb = 0; nb < 4; nb++)
#pragma unroll
      for (int r = 0; r < 4; r++)
        Pb[wave][quad * 4 + r][nb * 16 + n] = pbits[nb][r];
#pragma unroll
    for (int nb = 0; nb < 4; nb++)
#pragma unroll
      for (int r = 0; r < 4; r++) o_acc[nb][r] *= al[r];

    // ---- PV ----
#pragma unroll
    for (int c = 0; c < 2; c++) {
      bf16x8 pf = *(bf16x8*)&Pb[wave][n][c * 32 + quad * 8];
#pragma unroll
      for (int nb = 0; nb < 4; nb++) {
        bf16x8 vf = *(bf16x8*)&Vt[nb * 16 + n][c * 32 + quad * 8];
        o_acc[nb] = __builtin_amdgcn_mfma_f32_16x16x32_bf16(pf, vf, o_acc[nb], 0, 0, 0);
      }
    }
  }

#pragma unroll
  for (int r = 0; r < 4; r++) l_r[r] = 1.f / l_r[r];
#pragma unroll
  for (int nb = 0; nb < 4; nb++)
#pragma unroll
    for (int r = 0; r < 4; r++) {
      int row = qb * 64 + wave * 16 + quad * 4 + r;
      o[(size_t)row * 1024 + head * 64 + nb * 16 + n] = f2bf(o_acc[nb][r] * l_r[r]);
    }
}

// ---------------------------------------------------------------------------
// x = LayerNorm(x + delta)*g + b, in place; also writes bf16 copy xb
// ---------------------------------------------------------------------------
__global__ __launch_bounds__(256)
void add_ln_kernel(float* __restrict__ x, const float* __restrict__ d,
                   const float* __restrict__ g, const float* __restrict__ b,
                   short* __restrict__ xb)
{
  __shared__ float sb[4];
  const int row = blockIdx.x, tid = threadIdx.x;
  float* xr = x + (size_t)row * 1024;
  const float* dr = d + (size_t)row * 1024;

  float v[4]; float s = 0.f, ss = 0.f;
#pragma unroll
  for (int i = 0; i < 4; i++) {
    int c = tid + 256 * i;
    v[i] = xr[c] + dr[c];
    s += v[i]; ss += v[i] * v[i];
  }
#pragma unroll
  for (int off = 32; off; off >>= 1) { s += __shfl_down(s, off); ss += __shfl_down(ss, off); }
  const int lane = tid & 63, wid = tid >> 6;
  if (lane == 0) sb[wid] = s;
  __syncthreads();
  s = sb[0] + sb[1] + sb[2] + sb[3];
  __syncthreads();
  if (lane == 0) sb[wid] = ss;
  __syncthreads();
  ss = sb[0] + sb[1] + sb[2] + sb[3];

  float mean = s * (1.f / 1024.f);
  float var  = ss * (1.f / 1024.f) - mean * mean;
  float inv  = rsqrtf(var + 1e-5f);
#pragma unroll
  for (int i = 0; i < 4; i++) {
    int c = tid + 256 * i;
    float o = (v[i] - mean) * inv * g[c] + b[c];
    xr[c] = o;
    xb[(size_t)row * 1024 + c] = f2bf(o);
  }
}

// ---------------------------------------------------------------------------
// logits + softmax/entropy (unchanged, fp32)
// ---------------------------------------------------------------------------
__global__ __launch_bounds__(256)
void logits_kernel(const float* __restrict__ h1, const float* __restrict__ w2,
                   const float* __restrict__ b2, float* __restrict__ out)
{
  const int lane = threadIdx.x & 63;
  const int row = blockIdx.x * 4 + (threadIdx.x >> 6);
  const float* hr = h1 + (size_t)row * 512;
  float s = 0.f;
#pragma unroll
  for (int i = 0; i < 8; i++) s += hr[lane + 64 * i] * w2[lane + 64 * i];
#pragma unroll
  for (int off = 32; off; off >>= 1) s += __shfl_down(s, off);
  if (lane == 0) {
    out[4097 + row] = s + b2[0];
  }
}

__global__ __launch_bounds__(1024)
void softmax_entropy_kernel(const float* __restrict__ lg, float* __restrict__ out)
{
  __shared__ float sb[16];
  const int tid = threadIdx.x;
  const int lane = tid & 63, wid = tid >> 6;

  float l0[4];
#pragma unroll
  for (int i = 0; i < 4; i++) l0[i] = lg[tid + 1024 * i];

  float mx = fmaxf(fmaxf(l0[0], l0[1]), fmaxf(l0[2], l0[3]));
#pragma unroll
  for (int off = 32; off; off >>= 1) mx = fmaxf(mx, __shfl_down(mx, off));
  if (lane == 0) sb[wid] = mx;
  __syncthreads();
  if (tid == 0) { float m = sb[0]; for (int i = 1; i < 16; i++) m = fmaxf(m, sb[i]); sb[0] = m; }
  __syncthreads();
  mx = sb[0];
  __syncthreads();

  float e[4], s = 0.f;
#pragma unroll
  for (int i = 0; i < 4; i++) { e[i] = expf(l0[i] - mx); s += e[i]; }
#pragma unroll
  for (int off = 32; off; off >>= 1) s += __shfl_down(s, off);
  if (lane == 0) sb[wid] = s;
  __syncthreads();
  if (tid == 0) { float t = 0.f; for (int i = 0; i < 16; i++) t += sb[i]; sb[0] = t; }
  __syncthreads();
  float inv = 1.f / sb[0];
  __syncthreads();

  float h = 0.f;
#pragma unroll
  for (int i = 0; i < 4; i++) {
    float p = e[i] * inv;
    out[tid + 1024 * i] = p;
    h += p * logf(p + 1e-12f);
  }
#pragma unroll
  for (int off = 32; off; off >>= 1) h += __shfl_down(h, off);
  if (lane == 0) sb[wid] = h;
  __syncthreads();
  if (tid == 0) { float t = 0.f; for (int i = 0; i < 16; i++) t += sb[i]; out[4096] = -t; }
}

// ---------------------------------------------------------------------------
extern "C" void kernel_launch(void* const* d_in, const int* in_sizes, int n_in,
                              void* d_out, int out_size, void* d_ws, size_t ws_size,
                              hipStream_t stream)
{
  const float* node_emb   = (const float*)d_in[0];
  const int*   tile_ids   = (const int*)d_in[1];
  const float* entropies  = (const float*)d_in[2];
  const int*   Ny_p       = (const int*)d_in[3];
  const float* in_w       = (const float*)d_in[4];
  const float* in_b       = (const float*)d_in[5];
  const float* attn_in_w  = (const float*)d_in[6];
  const float* attn_in_b  = (const float*)d_in[7];
  const float* attn_out_w = (const float*)d_in[8];
  const float* attn_out_b = (const float*)d_in[9];
  const float* ff_w1      = (const float*)d_in[10];
  const float* ff_b1      = (const float*)d_in[11];
  const float* ff_w2      = (const float*)d_in[12];
  const float* ff_b2      = (const float*)d_in[13];
  const float* ln1_g      = (const float*)d_in[14];
  const float* ln1_b      = (const float*)d_in[15];
  const float* ln2_g      = (const float*)d_in[16];
  const float* ln2_b      = (const float*)d_in[17];
  const float* sh_w0      = (const float*)d_in[18];
  const float* sh_b0      = (const float*)d_in[19];
  const float* sh_w1      = (const float*)d_in[20];
  const float* sh_b1      = (const float*)d_in[21];
  const float* sh_w2      = (const float*)d_in[22];
  const float* sh_b2      = (const float*)d_in[23];
  float* out = (float*)d_out;

  // Workspace (byte offsets; peak 80 MB — same budget as known-good rounds).
  char* w8 = (char*)d_ws;
  float* X    = (float*)(w8);                        // [0,16M)  fp32 x, persistent
  short* Xb   = (short*)(w8 + (16u << 20));          // [16,24M) bf16 x
  short* XRb  = (short*)(w8 + (24u << 20));          // [24,32M) bf16 rope(x); later H0b
  short* QKb  = (short*)(w8 + (32u << 20));          // [32,48M) bf16 q|k; later Hb, H1
  short* Vb   = (short*)(w8 + (48u << 20));          // [48,56M) bf16 v
  short* Ob   = (short*)(w8 + (56u << 20));          // [56,64M) bf16 attn out; also A0b
  float* O2   = (float*)(w8 + (64u << 20));          // [64,80M) fp32 out-proj / ffn-out
  short* Hb   = QKb;
  short* A0b  = Ob;
  short* H0b  = XRb;
  float* H1   = (float*)(w8 + (32u << 20));

  // gather + convert node_emb rows
  gather_conv_kernel<<<UN * DN / 256, 256, 0, stream>>>(node_emb, tile_ids, A0b);

  // x = [gather, entropies] @ in_w.T + in_b  (K=1024 MFMA + rank-1 entropy col)
  gemm_bf16<<<dim3(32, 8), 256, 0, stream>>>(A0b, 1024, in_w, 1025, in_b,
      X, Xb, 1024, 1024, 0, entropies, in_w + 1024, 1025);

  for (int l = 0; l < LN_; l++) {
    const float* w_qkv = attn_in_w + (size_t)l * 3 * DN * DN;
    const float* b_qkv = attn_in_b + (size_t)l * 3 * DN;

    rope_kernel<<<UN * DN / 256, 256, 0, stream>>>(X, XRb, tile_ids, Ny_p);
    // q|k fused (N=2048)
    gemm_bf16<<<dim3(32, 16), 256, 0, stream>>>(XRb, 1024, w_qkv, 1024, b_qkv,
        nullptr, QKb, 2048, 1024, 0, nullptr, nullptr, 0);
    // v
    gemm_bf16<<<dim3(32, 8), 256, 0, stream>>>(Xb, 1024, w_qkv + (size_t)2048 * 1024, 1024,
        b_qkv + 2048, nullptr, Vb, 1024, 1024, 0, nullptr, nullptr, 0);
    attn_mfma_kernel<<<dim3(UN / 64, HN), 256, 0, stream>>>(QKb, Vb, Ob);
    gemm_bf16<<<dim3(32, 8), 256, 0, stream>>>(Ob, 1024, attn_out_w + (size_t)l * DN * DN, 1024,
        attn_out_b + (size_t)l * DN, O2, nullptr, 1024, 1024, 0, nullptr, nullptr, 0);
    add_ln_kernel<<<UN, 256, 0, stream>>>(X, O2, ln1_g + (size_t)l * DN, ln1_b + (size_t)l * DN, Xb);
    gemm_bf16<<<dim3(32, 16), 256, 0, stream>>>(Xb, 1024, ff_w1 + (size_t)l * 2 * DN * DN, 1024,
        ff_b1 + (size_t)l * 2 * DN, nullptr, Hb, 2048, 1024, 1, nullptr, nullptr, 0);
    gemm_bf16<<<dim3(32, 8), 256, 0, stream>>>(Hb, 2048, ff_w2 + (size_t)l * DN * 2 * DN, 2048,
        ff_b2 + (size_t)l * DN, O2, nullptr, 1024, 2048, 0, nullptr, nullptr, 0);
    add_ln_kernel<<<UN, 256, 0, stream>>>(X, O2, ln2_g + (size_t)l * DN, ln2_b + (size_t)l * DN, Xb);
  }

  // head MLP
  gemm_bf16<<<dim3(32, 4), 256, 0, stream>>>(Xb, 1024, sh_w0, 1024, sh_b0,
      nullptr, H0b, 512, 1024, 1, nullptr, nullptr, 0);
  gemm_bf16<<<dim3(32, 4), 256, 0, stream>>>(H0b, 512, sh_w1, 512, sh_b1,
      H1, nullptr, 512, 512, 1, nullptr, nullptr, 0);
  logits_kernel<<<UN / 4, 256, 0, stream>>>(H1, sh_w2, sh_b2, out);
  softmax_entropy_kernel<<<1, 1024, 0, stream>>>(out + 4097, out);
}